// Round 8
// baseline (135.261 us; speedup 1.0000x reference)
//
#include <hip/hip_runtime.h>
#include <hip/hip_bf16.h>
#include <hip/hip_cooperative_groups.h>
#include <math.h>

namespace cg = cooperative_groups;

#define NROW 256
#define DIM  65536
#define KB   256            // k-floats per block (256 split-K blocks)
#define CH   64             // k-floats per chunk
#define LSTR 72             // LDS row stride in ushorts (64 + 8 pad)
#define PSP  65600          // partial-buffer stride in ushorts (65536 + 64 pad)

typedef __attribute__((ext_vector_type(8))) short short8;
typedef __attribute__((ext_vector_type(4))) float f32x4;
typedef unsigned int       u32t;
typedef unsigned long long u64t;

__device__ __forceinline__ float bf2f(ushort h) {
    u32t u = ((u32t)h) << 16;
    return __builtin_bit_cast(float, u);
}
// packed fp32x2 -> bf16x2 (v_cvt_pk_bf16_f32, RNE)
__device__ __forceinline__ u32t pk2(float lo, float hi) {
    __hip_bfloat162 h = __float22bfloat162_rn(make_float2(lo, hi));
    u32t r; __builtin_memcpy(&r, &h, 4); return r;
}

// native-layout position of G[i][j] (matches gemm epilogue store order)
__device__ __forceinline__ int gpos(int i, int j) {
    const int wid  = ((i >> 7) << 2) | (j >> 6);
    const int lane = (((i >> 2) & 3) << 4) | (j & 15);
    const int m = (i >> 4) & 7, n = (j >> 4) & 3, jr = i & 3;
    return ((wid << 6) | lane) * 128 + (((m << 2) | n) << 2) + jr;
}

union LdsU {
    ushort es[2][NROW][LSTR];   // 73,728 B gemm staging (double-buffered chunks)
    float  sh[8][256];          // reduce / row_loss scratch
};

// ---------------------------------------------------------------------------
// One cooperative kernel, 256 blocks x 512 threads (1 block/CU):
//  Phase 1: split-K MFMA GEMM, 4 chunks of 64 k, double-buffered LDS.
//           Next chunk's global loads issue BEFORE the MFMA on the current
//           buffer (reg-only) -> memory latency hidden under compute; one
//           __syncthreads per chunk. bf16 partials, thread-native layout.
//  grid.sync()
//  Phase 2: reduce 256 partials -> Gn (native layout), 8 s-subgroups x
//           32-deep batched loads. Zeroes fixed-point accumulator.
//  grid.sync()
//  Phase 3: per-row softmax loss (block=row) + deterministic fixed-point
//           atomic total; last block writes out[0]. PSD term provably 0
//           (AM-GM, clipped at 0) - omitted.
// ---------------------------------------------------------------------------
__global__ __launch_bounds__(512, 2) void fused_k(const float* __restrict__ E,
                                                  ushort* __restrict__ part,
                                                  float* __restrict__ Gn,
                                                  const int* __restrict__ labels,
                                                  u64t* __restrict__ acc,
                                                  u32t* __restrict__ cnt,
                                                  float* __restrict__ out) {
    cg::grid_group grid = cg::this_grid();

    const int s    = blockIdx.x;
    const int tid  = threadIdx.x;
    const int lane = tid & 63;
    const int wid  = tid >> 6;
    const int wr   = wid >> 2;          // 0..1 -> 128-row band
    const int wc   = wid & 3;           // 0..3 -> 64-col band
    const int r15  = lane & 15;
    const int kgi  = lane >> 4;         // 0..3 -> 8-k slice within K=32

    __shared__ LdsU lds;

    // ---------------- Phase 1: GEMM ----------------
    {
        const int r8   = lane >> 3;     // row within 8-row group
        const int g    = lane & 7;      // 16B granule within 128B half
        const int rowb = wid * 32;
        const float* __restrict__ gb = E + (size_t)s * KB;

        f32x4 acc4[8][4];
        #pragma unroll
        for (int m = 0; m < 8; ++m)
            #pragma unroll
            for (int n = 0; n < 4; ++n) acc4[m][n] = (f32x4){0.f, 0.f, 0.f, 0.f};

        auto LOADC = [&](int c, float4* v) {
            #pragma unroll
            for (int u = 0; u < 8; ++u) {
                const int row = rowb + (u & 3) * 8 + r8;
                const int kf  = (u >> 2) * 32 + g * 4;
                v[u] = *(const float4*)(gb + ((size_t)row << 16) + c * CH + kf);
            }
        };
        auto WRITEC = [&](int buf, const float4* v) {
            #pragma unroll
            for (int u = 0; u < 8; ++u) {
                const int row = rowb + (u & 3) * 8 + r8;
                const int kf  = (u >> 2) * 32 + g * 4;
                uint2 wv;
                wv.x = pk2(v[u].x, v[u].y);
                wv.y = pk2(v[u].z, v[u].w);
                *(uint2*)&lds.es[buf][row][kf] = wv;
            }
        };

        float4 v0[8];
        LOADC(0, v0);
        WRITEC(0, v0);

        #pragma unroll
        for (int c = 0; c < 4; ++c) {
            __syncthreads();            // buf (c&1) staged; other buf free
            float4 vn[8];
            if (c < 3) LOADC(c + 1, vn);    // issue loads (no dependency)
            #pragma unroll
            for (int kk = 0; kk < 2; ++kk) {   // MFMA on buf (c&1)
                const int ko = kk * 32 + kgi * 8;
                short8 af[8], bfr[4];
                #pragma unroll
                for (int m = 0; m < 8; ++m)
                    af[m] = *(const short8*)&lds.es[c & 1][wr * 128 + m * 16 + r15][ko];
                #pragma unroll
                for (int n = 0; n < 4; ++n)
                    bfr[n] = *(const short8*)&lds.es[c & 1][wc * 64 + n * 16 + r15][ko];
                #pragma unroll
                for (int m = 0; m < 8; ++m)
                    #pragma unroll
                    for (int n = 0; n < 4; ++n)
                        acc4[m][n] = __builtin_amdgcn_mfma_f32_16x16x32_bf16(
                            af[m], bfr[n], acc4[m][n], 0, 0, 0);
            }
            if (c < 3) WRITEC((c + 1) & 1, vn);   // waits vmcnt, fills other buf
        }

        // epilogue: 128 accs -> bf16, contiguous per-thread (16B stores)
        ushort* pp = part + (size_t)s * PSP + (size_t)tid * 128;
        #pragma unroll
        for (int m = 0; m < 8; ++m)
            #pragma unroll
            for (int n = 0; n < 4; n += 2) {
                uint4 q;
                q.x = pk2(acc4[m][n][0],     acc4[m][n][1]);
                q.y = pk2(acc4[m][n][2],     acc4[m][n][3]);
                q.z = pk2(acc4[m][n + 1][0], acc4[m][n + 1][1]);
                q.w = pk2(acc4[m][n + 1][2], acc4[m][n + 1][3]);
                *(uint4*)(pp + ((m << 2) | n) * 4) = q;
            }
    }

    grid.sync();

    // ---------------- Phase 2: reduce partials -> Gn ----------------
    {
        if (blockIdx.x == 0 && tid == 0) { *acc = 0ull; *cnt = 0u; }

        const int b  = blockIdx.x;
        const int l  = tid & 63, sg = tid >> 6;      // 8 s-subgroups
        const int n0 = b * 256 + l * 4;
        const ushort* base = part + (size_t)(sg * 32) * PSP + n0;

        uint2 r[32];
        #pragma unroll
        for (int u = 0; u < 32; ++u)
            r[u] = *(const uint2*)(base + (size_t)u * PSP);

        float a0 = 0.f, a1 = 0.f, a2 = 0.f, a3 = 0.f;
        #pragma unroll
        for (int u = 0; u < 32; ++u) {
            a0 += bf2f((ushort)(r[u].x & 0xffffu));
            a1 += bf2f((ushort)(r[u].x >> 16));
            a2 += bf2f((ushort)(r[u].y & 0xffffu));
            a3 += bf2f((ushort)(r[u].y >> 16));
        }
        lds.sh[sg][l * 4 + 0] = a0; lds.sh[sg][l * 4 + 1] = a1;
        lds.sh[sg][l * 4 + 2] = a2; lds.sh[sg][l * 4 + 3] = a3;
        __syncthreads();
        if (tid < 256) {
            const float t0 = ((lds.sh[0][tid] + lds.sh[1][tid]) +
                              (lds.sh[2][tid] + lds.sh[3][tid])) +
                             ((lds.sh[4][tid] + lds.sh[5][tid]) +
                              (lds.sh[6][tid] + lds.sh[7][tid]));
            Gn[b * 256 + tid] = t0;
        }
    }

    grid.sync();

    // ---------------- Phase 3: row loss + deterministic total ----------------
    {
        const int i   = blockIdx.x;
        const int j   = tid;
        const bool act = (tid < 256);
        float* redZ = &lds.sh[0][0];
        float* redN = &lds.sh[0][8];

        float sc = -3.0e38f;
        bool diag = false;
        if (act) {
            const float Gii = Gn[gpos(i, i)];
            const float Gjj = Gn[gpos(j, j)];
            const float Gij = Gn[gpos(i, j)];
            const float d2 = fmaxf(Gii + Gjj - 2.0f * Gij, 0.0f);
            diag = (j == i);
            sc = diag ? -3.0e38f : -sqrtf(d2);
        }

        float m = sc;
        #pragma unroll
        for (int off = 32; off; off >>= 1) m = fmaxf(m, __shfl_xor(m, off, 64));
        if (act && (j & 63) == 0) redZ[j >> 6] = m;
        __syncthreads();
        m = fmaxf(fmaxf(redZ[0], redZ[1]), fmaxf(redZ[2], redZ[3]));

        const float p  = (act && !diag) ? expf(sc - m) : 0.0f;
        const float nm = (act && labels[j] == labels[i]) ? p : 0.0f;

        float zs = p, ns = nm;
        #pragma unroll
        for (int off = 32; off; off >>= 1) {
            zs += __shfl_xor(zs, off, 64);
            ns += __shfl_xor(ns, off, 64);
        }
        __syncthreads();    // WAR guard on redZ
        if (act && (j & 63) == 0) { redZ[j >> 6] = zs; redN[j >> 6] = ns; }
        __syncthreads();
        if (tid == 0) {
            const float Z = (redZ[0] + redZ[1]) + (redZ[2] + redZ[3]);
            const float N = (redN[0] + redN[1]) + (redN[2] + redN[3]);
            const float rl = logf(Z) - logf(N);      // >= 0 (N subset of Z)
            const long long q = llrintf(rl * 1048576.0f);
            atomicAdd(acc, (u64t)q);
            __threadfence();
            const u32t c = atomicAdd(cnt, 1u);
            if (c == NROW - 1) {
                __threadfence();
                const u64t tot = atomicAdd(acc, 0ull);
                out[0] = (float)((double)(long long)tot * (1.0 / 1048576.0) * 0.005);
            }
        }
    }
}

extern "C" void kernel_launch(void* const* d_in, const int* in_sizes, int n_in,
                              void* d_out, int out_size, void* d_ws, size_t ws_size,
                              hipStream_t stream) {
    const float* E      = (const float*)d_in[0];
    const int*   labels = (const int*)d_in[1];
    float*       out    = (float*)d_out;

    ushort* part = (ushort*)d_ws;                         // 256 * PSP ushorts
    float*  Gn   = (float*)((char*)d_ws + (size_t)256 * PSP * sizeof(ushort));
    u64t*   acc  = (u64t*)(Gn + NROW * NROW);
    u32t*   cnt  = (u32t*)(acc + 1);

    void* args[] = {(void*)&E, (void*)&part, (void*)&Gn, (void*)&labels,
                    (void*)&acc, (void*)&cnt, (void*)&out};
    hipLaunchCooperativeKernel((const void*)fused_k, dim3(256), dim3(512),
                               args, 0, stream);
}

// Round 9
// 45.743 us; speedup vs baseline: 2.9570x; 2.9570x over previous
//
#include <hip/hip_runtime.h>
#include <hip/hip_bf16.h>
#include <math.h>

#define NROW 256
#define DIM  65536
#define KB   256            // k-floats per block (256 split-K blocks)
#define CH   64             // k-floats per chunk (4 chunks)
#define LSTR 72             // LDS row stride in ushorts (64 + 8 pad)
#define PSP  65600          // partial-buffer stride in ushorts (65536 + 64 pad)

typedef __attribute__((ext_vector_type(8))) short short8;
typedef __attribute__((ext_vector_type(4))) float f32x4;
typedef unsigned int       u32t;
typedef unsigned long long u64t;

__device__ __forceinline__ float bf2f(ushort h) {
    u32t u = ((u32t)h) << 16;
    return __builtin_bit_cast(float, u);
}
// packed fp32x2 -> bf16x2 (v_cvt_pk_bf16_f32, RNE)
__device__ __forceinline__ u32t pk2(float lo, float hi) {
    __hip_bfloat162 h = __float22bfloat162_rn(make_float2(lo, hi));
    u32t r; __builtin_memcpy(&r, &h, 4); return r;
}

// native-layout position of G[i][j] (matches gemm epilogue store order)
__device__ __forceinline__ int gpos(int i, int j) {
    const int wid  = ((i >> 7) << 2) | (j >> 6);
    const int lane = (((i >> 2) & 3) << 4) | (j & 15);
    const int m = (i >> 4) & 7, n = (j >> 4) & 3, jr = i & 3;
    return ((wid << 6) | lane) * 128 + (((m << 2) | n) << 2) + jr;
}

// ---------------------------------------------------------------------------
// Split-K MFMA GEMM, chunked double-buffer (4 chunks x K=64), 2 blocks/CU.
// Per chunk: issue next chunk's 8 float4 loads (32 VGPRs staged) -> 64 MFMAs
// on current LDS buffer while loads fly -> cvt_pk + ds_write other buffer ->
// one __syncthreads. Cross-block overlap (2/CU) covers epilogue + barriers.
// Partials bf16, thread-native layout, padded stride.
// ---------------------------------------------------------------------------
__global__ __launch_bounds__(512, 2) void gemm_k(const float* __restrict__ E,
                                                 ushort* __restrict__ part) {
    const int s    = blockIdx.x;
    const int tid  = threadIdx.x;
    const int lane = tid & 63;
    const int wid  = tid >> 6;
    const int wr   = wid >> 2;          // 0..1 -> 128-row band
    const int wc   = wid & 3;           // 0..3 -> 64-col band
    const int r15  = lane & 15;
    const int kgi  = lane >> 4;         // 0..3 -> 8-k slice within K=32

    __shared__ ushort es[2][NROW][LSTR];   // 73,728 B -> 2 blocks/CU

    const int r8   = lane >> 3;         // row within 8-row group
    const int g    = lane & 7;          // 16B granule within 128B half
    const int rowb = wid * 32;
    const float* __restrict__ gb = E + (size_t)s * KB;

    f32x4 acc4[8][4];
    #pragma unroll
    for (int m = 0; m < 8; ++m)
        #pragma unroll
        for (int n = 0; n < 4; ++n) acc4[m][n] = (f32x4){0.f, 0.f, 0.f, 0.f};

    auto LOADC = [&](int c, float4* v) {
        #pragma unroll
        for (int u = 0; u < 8; ++u) {
            const int row = rowb + (u & 3) * 8 + r8;
            const int kf  = (u >> 2) * 32 + g * 4;
            v[u] = *(const float4*)(gb + ((size_t)row << 16) + c * CH + kf);
        }
    };
    auto WRITEC = [&](int buf, const float4* v) {
        #pragma unroll
        for (int u = 0; u < 8; ++u) {
            const int row = rowb + (u & 3) * 8 + r8;
            const int kf  = (u >> 2) * 32 + g * 4;
            uint2 wv;
            wv.x = pk2(v[u].x, v[u].y);
            wv.y = pk2(v[u].z, v[u].w);
            *(uint2*)&es[buf][row][kf] = wv;
        }
    };

    float4 v0[8];
    LOADC(0, v0);
    WRITEC(0, v0);

    #pragma unroll
    for (int c = 0; c < 4; ++c) {
        __syncthreads();                // buf (c&1) staged; reads of other done
        float4 vn[8];
        if (c < 3) LOADC(c + 1, vn);    // issue next chunk's loads early
        #pragma unroll
        for (int kk = 0; kk < 2; ++kk) {    // MFMA on buf (c&1)
            const int ko = kk * 32 + kgi * 8;
            short8 af[8], bfr[4];
            #pragma unroll
            for (int m = 0; m < 8; ++m)
                af[m] = *(const short8*)&es[c & 1][wr * 128 + m * 16 + r15][ko];
            #pragma unroll
            for (int n = 0; n < 4; ++n)
                bfr[n] = *(const short8*)&es[c & 1][wc * 64 + n * 16 + r15][ko];
            #pragma unroll
            for (int m = 0; m < 8; ++m)
                #pragma unroll
                for (int n = 0; n < 4; ++n)
                    acc4[m][n] = __builtin_amdgcn_mfma_f32_16x16x32_bf16(
                        af[m], bfr[n], acc4[m][n], 0, 0, 0);
        }
        if (c < 3) WRITEC((c + 1) & 1, vn);   // waits vmcnt, fills other buf
    }

    // epilogue: 128 accs -> bf16, contiguous per-thread (coalesced 16B stores)
    ushort* pp = part + (size_t)s * PSP + (size_t)tid * 128;
    #pragma unroll
    for (int m = 0; m < 8; ++m)
        #pragma unroll
        for (int n = 0; n < 4; n += 2) {
            uint4 q;
            q.x = pk2(acc4[m][n][0],     acc4[m][n][1]);
            q.y = pk2(acc4[m][n][2],     acc4[m][n][3]);
            q.z = pk2(acc4[m][n + 1][0], acc4[m][n + 1][1]);
            q.w = pk2(acc4[m][n + 1][2], acc4[m][n + 1][3]);
            *(uint4*)(pp + ((m << 2) | n) * 4) = q;
        }
}

// ---------------------------------------------------------------------------
// Partial reduction, 512 blocks (2/CU): block (h, b) sums s-half h over a
// 512 B position window, 32 loads batched in flight. Writes Gh[h][pos].
// Deterministic fixed tree: u-ascending, then sg 0..3, then h0+h1 (row_loss).
// Also zeroes the fixed-point accumulator for row_loss (stream-ordered).
// ---------------------------------------------------------------------------
__global__ __launch_bounds__(256) void reduce_k(const ushort* __restrict__ part,
                                                float* __restrict__ Gh,
                                                u64t* __restrict__ acc,
                                                u32t* __restrict__ cnt) {
    if (blockIdx.x == 0 && threadIdx.x == 0) { *acc = 0ull; *cnt = 0u; }

    const int b = blockIdx.x & 255;     // position window
    const int h = blockIdx.x >> 8;      // s half
    const int t = threadIdx.x, l = t & 63, sg = t >> 6;
    const int n0 = b * 256 + l * 4;

    const ushort* base = part + (size_t)(h * 128 + sg) * PSP + n0;

    uint2 r[32];
    #pragma unroll
    for (int u = 0; u < 32; ++u)
        r[u] = *(const uint2*)(base + (size_t)(4 * u) * PSP);

    float a0 = 0.f, a1 = 0.f, a2 = 0.f, a3 = 0.f;
    #pragma unroll
    for (int u = 0; u < 32; ++u) {
        a0 += bf2f((ushort)(r[u].x & 0xffffu));
        a1 += bf2f((ushort)(r[u].x >> 16));
        a2 += bf2f((ushort)(r[u].y & 0xffffu));
        a3 += bf2f((ushort)(r[u].y >> 16));
    }
    __shared__ float sh[4][256];
    sh[sg][l * 4 + 0] = a0; sh[sg][l * 4 + 1] = a1;
    sh[sg][l * 4 + 2] = a2; sh[sg][l * 4 + 3] = a3;
    __syncthreads();
    Gh[(size_t)h * 65536 + b * 256 + t] =
        (sh[0][t] + sh[1][t]) + (sh[2][t] + sh[3][t]);
}

// ---------------------------------------------------------------------------
// Fused per-row softmax loss + deterministic final sum (fixed-point atomic,
// order-independent). PSD term provably 0 (AM-GM; clip at 0), omitted.
// ---------------------------------------------------------------------------
__global__ __launch_bounds__(256) void row_loss_k(const float* __restrict__ Gh,
                                                  const int* __restrict__ labels,
                                                  u64t* __restrict__ acc,
                                                  u32t* __restrict__ cnt,
                                                  float* __restrict__ out) {
    const int i = blockIdx.x;
    const int j = threadIdx.x;

    const int pii = gpos(i, i), pjj = gpos(j, j), pij = gpos(i, j);
    const float Gii = Gh[pii] + Gh[65536 + pii];
    const float Gjj = Gh[pjj] + Gh[65536 + pjj];
    const float Gij = Gh[pij] + Gh[65536 + pij];
    const float d2 = fmaxf(Gii + Gjj - 2.0f * Gij, 0.0f);
    const bool diag = (j == i);
    const float sc = diag ? -3.0e38f : -sqrtf(d2);

    __shared__ float red0[4], red1[4];

    float m = sc;
    #pragma unroll
    for (int off = 32; off; off >>= 1) m = fmaxf(m, __shfl_xor(m, off, 64));
    const int w = j >> 6;
    if ((j & 63) == 0) red0[w] = m;
    __syncthreads();
    m = fmaxf(fmaxf(red0[0], red0[1]), fmaxf(red0[2], red0[3]));

    const float p  = diag ? 0.0f : expf(sc - m);
    const float nm = (labels[j] == labels[i]) ? p : 0.0f;

    float zs = p, ns = nm;
    #pragma unroll
    for (int off = 32; off; off >>= 1) {
        zs += __shfl_xor(zs, off, 64);
        ns += __shfl_xor(ns, off, 64);
    }
    __syncthreads();
    if ((j & 63) == 0) { red0[w] = zs; red1[w] = ns; }
    __syncthreads();
    if (j == 0) {
        const float Z = red0[0] + red0[1] + red0[2] + red0[3];
        const float N = red1[0] + red1[1] + red1[2] + red1[3];
        const float rl = logf(Z) - logf(N);          // >= 0 (N subset of Z)
        const long long q = llrintf(rl * 1048576.0f);
        atomicAdd(acc, (u64t)q);
        __threadfence();
        const u32t c = atomicAdd(cnt, 1u);
        if (c == NROW - 1) {
            __threadfence();
            const u64t tot = atomicAdd(acc, 0ull);
            out[0] = (float)((double)(long long)tot * (1.0 / 1048576.0) * 0.005);
        }
    }
}

extern "C" void kernel_launch(void* const* d_in, const int* in_sizes, int n_in,
                              void* d_out, int out_size, void* d_ws, size_t ws_size,
                              hipStream_t stream) {
    const float* E      = (const float*)d_in[0];
    const int*   labels = (const int*)d_in[1];
    float*       out    = (float*)d_out;

    ushort* part = (ushort*)d_ws;                         // 256 * PSP ushorts
    float*  Gh   = (float*)((char*)d_ws + (size_t)256 * PSP * sizeof(ushort));
    u64t*   acc  = (u64t*)(Gh + 2 * NROW * NROW);
    u32t*   cnt  = (u32t*)(acc + 1);

    gemm_k    <<<256, 512, 0, stream>>>(E, part);
    reduce_k  <<<512, 256, 0, stream>>>(part, Gh, acc, cnt);
    row_loss_k<<<NROW, 256, 0, stream>>>(Gh, labels, acc, cnt, out);
}